// Round 1
// baseline (26708.182 us; speedup 1.0000x reference)
//
#include <hip/hip_runtime.h>
#include <stdint.h>

#define TT 512
#define BB 64
#define EE 512
#define HH1 512
#define HH2 256
#define NTAGS 48

typedef __attribute__((ext_vector_type(8))) short bf16x8;
typedef __attribute__((ext_vector_type(4))) float f32x4;

__device__ inline unsigned short f2bf(float f) {
  union { float f; unsigned u; } v; v.f = f;
  unsigned r = v.u + 0x7fffu + ((v.u >> 16) & 1u);
  return (unsigned short)(r >> 16);
}
__device__ inline float sigf(float x) { return 1.0f / (1.0f + __expf(-x)); }
__device__ inline float tanhfast(float x) { return 1.0f - 2.0f / (__expf(2.0f * x) + 1.0f); }

// ---- inter-block barrier: one fresh slot per (group, step); slots zeroed per launch ----
__device__ inline void groupbar(unsigned* slot, unsigned target) {
  __syncthreads();
  if (threadIdx.x == 0) {
    __threadfence();
    __hip_atomic_fetch_add(slot, 1u, __ATOMIC_RELEASE, __HIP_MEMORY_SCOPE_AGENT);
    while (__hip_atomic_load(slot, __ATOMIC_ACQUIRE, __HIP_MEMORY_SCOPE_AGENT) < target) {
      __builtin_amdgcn_s_sleep(4);
    }
  }
  __syncthreads();
}

// ---- x[t][b][k] = bf16(embed[seq[b][t]][k]) ----
__global__ void k_gather_x(const float* __restrict__ emb, const int* __restrict__ seq,
                           unsigned short* __restrict__ x) {
  size_t i4 = ((size_t)blockIdx.x * 256 + threadIdx.x) * 4;  // < T*B*512
  int r = (int)(i4 >> 9);
  int k = (int)(i4 & 511);
  int t = r >> 6, b = r & 63;
  int tok = seq[b * TT + t];
  float4 v = *(const float4*)(emb + (size_t)tok * EE + k);
  unsigned short* dst = x + i4;
  dst[0] = f2bf(v.x); dst[1] = f2bf(v.y); dst[2] = f2bf(v.z); dst[3] = f2bf(v.w);
}

// ---- W1cat[d][n][k]: k<512 from w_ih1, else w_hh1 (bf16) ----
__global__ void k_conv_w1(const float* __restrict__ wihf, const float* __restrict__ whhf,
                          const float* __restrict__ wihb, const float* __restrict__ whhb,
                          unsigned short* __restrict__ W) {
  size_t i4 = ((size_t)blockIdx.x * 256 + threadIdx.x) * 4;  // < 2*2048*1024
  int d = (int)(i4 >> 21);
  int rem = (int)(i4 & ((1u << 21) - 1));
  int n = rem >> 10;
  int k = rem & 1023;
  const float* src = (k < 512) ? ((d ? wihb : wihf) + (size_t)n * 512 + k)
                               : ((d ? whhb : whhf) + (size_t)n * 512 + (k - 512));
  float4 v = *(const float4*)src;
  unsigned short* dst = W + i4;
  dst[0] = f2bf(v.x); dst[1] = f2bf(v.y); dst[2] = f2bf(v.z); dst[3] = f2bf(v.w);
}

// ---- W2cat[d][n][k]: [1024][1280], k<1024 from w_ih2, else w_hh2 ----
__global__ void k_conv_w2(const float* __restrict__ wihf, const float* __restrict__ whhf,
                          const float* __restrict__ wihb, const float* __restrict__ whhb,
                          unsigned short* __restrict__ W) {
  size_t i4 = ((size_t)blockIdx.x * 256 + threadIdx.x) * 4;  // < 2*1024*1280
  int d = (int)(i4 / 1310720);
  int rem = (int)(i4 % 1310720);
  int n = rem / 1280;
  int k = rem % 1280;
  const float* src = (k < 1024) ? ((d ? wihb : wihf) + (size_t)n * 1024 + k)
                                : ((d ? whhb : whhf) + (size_t)n * 256 + (k - 1024));
  float4 v = *(const float4*)src;
  unsigned short* dst = W + i4;
  dst[0] = f2bf(v.x); dst[1] = f2bf(v.y); dst[2] = f2bf(v.z); dst[3] = f2bf(v.w);
}

// ---- small stuff: Wlin bf16, bias sums, initial h/c states ----
__global__ void k_misc_init(const float* __restrict__ linw,
                            const float* __restrict__ h0, const float* __restrict__ c0,
                            const float* __restrict__ h1, const float* __restrict__ c1,
                            const float* __restrict__ bi1f, const float* __restrict__ bh1f,
                            const float* __restrict__ bi1b, const float* __restrict__ bh1b,
                            const float* __restrict__ bi2f, const float* __restrict__ bh2f,
                            const float* __restrict__ bi2b, const float* __restrict__ bh2b,
                            unsigned short* __restrict__ wlin, float* __restrict__ bsum1,
                            float* __restrict__ bsum2, unsigned short* __restrict__ h1b,
                            float* __restrict__ c1b, unsigned short* __restrict__ h2b,
                            float* __restrict__ c2b) {
  int i = blockIdx.x * 256 + threadIdx.x;
  if (i < 24576) { wlin[i] = f2bf(linw[i]); return; }
  i -= 24576;
  if (i < 4096) {
    int d = i >> 11, n = i & 2047;
    bsum1[i] = d ? (bi1b[n] + bh1b[n]) : (bi1f[n] + bh1f[n]);
    return;
  }
  i -= 4096;
  if (i < 2048) {
    int d = i >> 10, n = i & 1023;
    bsum2[i] = d ? (bi2b[n] + bh2b[n]) : (bi2f[n] + bh2f[n]);
    return;
  }
  i -= 2048;
  if (i < 65536) { h1b[i] = f2bf(h0[i]); return; }  // phase0: [2][64][512]
  i -= 65536;
  if (i < 65536) { c1b[i] = c0[i]; return; }
  i -= 65536;
  if (i < 32768) { h2b[i] = f2bf(h1[i]); return; }  // phase0: [2][64][256]
  i -= 32768;
  if (i < 32768) { c2b[i] = c1[i]; return; }
}

// ---- persistent BiLSTM layer 1: 64 blocks (32 fwd, 32 bwd) x 256 threads ----
__global__ __launch_bounds__(256) void k_lstm1(
    const unsigned short* __restrict__ x,     // [T][B][512] bf16
    const unsigned short* __restrict__ W,     // [2][2048][1024] bf16
    const float* __restrict__ bsum,           // [2][2048]
    unsigned short* __restrict__ hbuf,        // [2 phase][2 dir][B][512] bf16
    float* __restrict__ cbuf,                 // [2 dir][B][512]
    unsigned short* __restrict__ out1,        // [T][B][1024] bf16
    unsigned* __restrict__ bars) {            // [4][512]
  const int dir  = blockIdx.x >> 5;
  const int wb   = blockIdx.x & 31;
  const int wave = threadIdx.x >> 6;
  const int lane = threadIdx.x & 63;
  const int tile = wb * 4 + wave;   // 0..127
  const int bt = tile >> 5;         // 0..3
  const int ut = tile & 31;         // 0..31
  const int r16 = lane & 15;
  const int kg  = lane >> 4;
  const int brow = bt * 16 + r16;
  const int unit = ut * 16 + r16;

  const unsigned short* Wd = W + (size_t)dir * 2048 * 1024 + (size_t)kg * 8;
  const unsigned short* w0 = Wd + (size_t)(0 * 512 + unit) * 1024;
  const unsigned short* w1 = Wd + (size_t)(1 * 512 + unit) * 1024;
  const unsigned short* w2 = Wd + (size_t)(2 * 512 + unit) * 1024;
  const unsigned short* w3 = Wd + (size_t)(3 * 512 + unit) * 1024;
  const float b0 = bsum[dir * 2048 + 0 * 512 + unit];
  const float b1 = bsum[dir * 2048 + 1 * 512 + unit];
  const float b2 = bsum[dir * 2048 + 2 * 512 + unit];
  const float b3 = bsum[dir * 2048 + 3 * 512 + unit];
  unsigned* mybars = bars + dir * TT;

  for (int s = 0; s < TT; ++s) {
    const int t = dir ? (TT - 1 - s) : s;
    const int rp = s & 1;
    const unsigned short* xr = x + ((size_t)t * BB + brow) * 512 + kg * 8;
    const unsigned short* hr = hbuf + (((size_t)rp * 2 + dir) * BB + brow) * 512 + kg * 8;
    f32x4 a0 = {0.f, 0.f, 0.f, 0.f}, a1 = a0, a2 = a0, a3 = a0;
    #pragma unroll 4
    for (int kk = 0; kk < 16; ++kk) {
      bf16x8 av = *(const bf16x8*)(xr + kk * 32);
      a0 = __builtin_amdgcn_mfma_f32_16x16x32_bf16(av, *(const bf16x8*)(w0 + kk * 32), a0, 0, 0, 0);
      a1 = __builtin_amdgcn_mfma_f32_16x16x32_bf16(av, *(const bf16x8*)(w1 + kk * 32), a1, 0, 0, 0);
      a2 = __builtin_amdgcn_mfma_f32_16x16x32_bf16(av, *(const bf16x8*)(w2 + kk * 32), a2, 0, 0, 0);
      a3 = __builtin_amdgcn_mfma_f32_16x16x32_bf16(av, *(const bf16x8*)(w3 + kk * 32), a3, 0, 0, 0);
    }
    #pragma unroll 4
    for (int kk = 0; kk < 16; ++kk) {
      bf16x8 av = *(const bf16x8*)(hr + kk * 32);
      a0 = __builtin_amdgcn_mfma_f32_16x16x32_bf16(av, *(const bf16x8*)(w0 + 512 + kk * 32), a0, 0, 0, 0);
      a1 = __builtin_amdgcn_mfma_f32_16x16x32_bf16(av, *(const bf16x8*)(w1 + 512 + kk * 32), a1, 0, 0, 0);
      a2 = __builtin_amdgcn_mfma_f32_16x16x32_bf16(av, *(const bf16x8*)(w2 + 512 + kk * 32), a2, 0, 0, 0);
      a3 = __builtin_amdgcn_mfma_f32_16x16x32_bf16(av, *(const bf16x8*)(w3 + 512 + kk * 32), a3, 0, 0, 0);
    }
    #pragma unroll
    for (int rr = 0; rr < 4; ++rr) {
      const int batch = bt * 16 + kg * 4 + rr;  // C layout: row=(lane>>4)*4+reg, col=lane&15
      float iv = a0[rr] + b0, fv = a1[rr] + b1, gv = a2[rr] + b2, ov = a3[rr] + b3;
      float* cp = cbuf + ((size_t)dir * BB + batch) * 512 + unit;
      float cn = sigf(fv) * cp[0] + sigf(iv) * tanhfast(gv);
      float hn = sigf(ov) * tanhfast(cn);
      cp[0] = cn;
      unsigned short hb = f2bf(hn);
      hbuf[(((size_t)(rp ^ 1) * 2 + dir) * BB + batch) * 512 + unit] = hb;
      out1[((size_t)t * BB + batch) * 1024 + dir * 512 + unit] = hb;
    }
    if (s != TT - 1) groupbar(&mybars[s], 32u);
  }
}

// ---- persistent BiLSTM layer 2: 32 blocks (16 fwd, 16 bwd) x 256 threads ----
__global__ __launch_bounds__(256) void k_lstm2(
    const unsigned short* __restrict__ in,    // out1 [T][B][1024] bf16
    const unsigned short* __restrict__ W,     // [2][1024][1280] bf16
    const float* __restrict__ bsum,           // [2][1024]
    unsigned short* __restrict__ hbuf,        // [2 phase][2 dir][B][256] bf16
    float* __restrict__ cbuf,                 // [2 dir][B][256]
    unsigned short* __restrict__ out2,        // [T][B][512] bf16
    unsigned* __restrict__ bars) {
  const int dir  = blockIdx.x >> 4;
  const int wb   = blockIdx.x & 15;
  const int wave = threadIdx.x >> 6;
  const int lane = threadIdx.x & 63;
  const int tile = wb * 4 + wave;   // 0..63
  const int bt = tile >> 4;         // 0..3
  const int ut = tile & 15;         // 0..15
  const int r16 = lane & 15;
  const int kg  = lane >> 4;
  const int brow = bt * 16 + r16;
  const int unit = ut * 16 + r16;

  const unsigned short* Wd = W + (size_t)dir * 1024 * 1280 + (size_t)kg * 8;
  const unsigned short* w0 = Wd + (size_t)(0 * 256 + unit) * 1280;
  const unsigned short* w1 = Wd + (size_t)(1 * 256 + unit) * 1280;
  const unsigned short* w2 = Wd + (size_t)(2 * 256 + unit) * 1280;
  const unsigned short* w3 = Wd + (size_t)(3 * 256 + unit) * 1280;
  const float b0 = bsum[dir * 1024 + 0 * 256 + unit];
  const float b1 = bsum[dir * 1024 + 1 * 256 + unit];
  const float b2 = bsum[dir * 1024 + 2 * 256 + unit];
  const float b3 = bsum[dir * 1024 + 3 * 256 + unit];
  unsigned* mybars = bars + (2 + dir) * TT;

  for (int s = 0; s < TT; ++s) {
    const int t = dir ? (TT - 1 - s) : s;
    const int rp = s & 1;
    const unsigned short* xr = in + ((size_t)t * BB + brow) * 1024 + kg * 8;
    const unsigned short* hr = hbuf + (((size_t)rp * 2 + dir) * BB + brow) * 256 + kg * 8;
    f32x4 a0 = {0.f, 0.f, 0.f, 0.f}, a1 = a0, a2 = a0, a3 = a0;
    #pragma unroll 4
    for (int kk = 0; kk < 32; ++kk) {
      bf16x8 av = *(const bf16x8*)(xr + kk * 32);
      a0 = __builtin_amdgcn_mfma_f32_16x16x32_bf16(av, *(const bf16x8*)(w0 + kk * 32), a0, 0, 0, 0);
      a1 = __builtin_amdgcn_mfma_f32_16x16x32_bf16(av, *(const bf16x8*)(w1 + kk * 32), a1, 0, 0, 0);
      a2 = __builtin_amdgcn_mfma_f32_16x16x32_bf16(av, *(const bf16x8*)(w2 + kk * 32), a2, 0, 0, 0);
      a3 = __builtin_amdgcn_mfma_f32_16x16x32_bf16(av, *(const bf16x8*)(w3 + kk * 32), a3, 0, 0, 0);
    }
    #pragma unroll 4
    for (int kk = 0; kk < 8; ++kk) {
      bf16x8 av = *(const bf16x8*)(hr + kk * 32);
      a0 = __builtin_amdgcn_mfma_f32_16x16x32_bf16(av, *(const bf16x8*)(w0 + 1024 + kk * 32), a0, 0, 0, 0);
      a1 = __builtin_amdgcn_mfma_f32_16x16x32_bf16(av, *(const bf16x8*)(w1 + 1024 + kk * 32), a1, 0, 0, 0);
      a2 = __builtin_amdgcn_mfma_f32_16x16x32_bf16(av, *(const bf16x8*)(w2 + 1024 + kk * 32), a2, 0, 0, 0);
      a3 = __builtin_amdgcn_mfma_f32_16x16x32_bf16(av, *(const bf16x8*)(w3 + 1024 + kk * 32), a3, 0, 0, 0);
    }
    #pragma unroll
    for (int rr = 0; rr < 4; ++rr) {
      const int batch = bt * 16 + kg * 4 + rr;
      float iv = a0[rr] + b0, fv = a1[rr] + b1, gv = a2[rr] + b2, ov = a3[rr] + b3;
      float* cp = cbuf + ((size_t)dir * BB + batch) * 256 + unit;
      float cn = sigf(fv) * cp[0] + sigf(iv) * tanhfast(gv);
      float hn = sigf(ov) * tanhfast(cn);
      cp[0] = cn;
      unsigned short hb = f2bf(hn);
      hbuf[(((size_t)(rp ^ 1) * 2 + dir) * BB + batch) * 256 + unit] = hb;
      out2[((size_t)t * BB + batch) * 512 + dir * 256 + unit] = hb;
    }
    if (s != TT - 1) groupbar(&mybars[s], 16u);
  }
}

// ---- logits = out2 @ lin_w^T + lin_b : [32768][48] f32 ----
__global__ __launch_bounds__(256) void k_linear(const unsigned short* __restrict__ out2,
                                                const unsigned short* __restrict__ wl,
                                                const float* __restrict__ lb,
                                                float* __restrict__ logits) {
  const int wid = blockIdx.x * 4 + (threadIdx.x >> 6);  // < 6144
  const int lane = threadIdx.x & 63;
  const int mt = wid / 3, nt = wid % 3;
  const int r16 = lane & 15, kg = lane >> 4;
  const unsigned short* ar = out2 + ((size_t)mt * 16 + r16) * 512 + kg * 8;
  const unsigned short* br = wl + ((size_t)(nt * 16 + r16)) * 512 + kg * 8;
  f32x4 acc = {0.f, 0.f, 0.f, 0.f};
  #pragma unroll
  for (int kk = 0; kk < 16; ++kk) {
    bf16x8 av = *(const bf16x8*)(ar + kk * 32);
    bf16x8 bv = *(const bf16x8*)(br + kk * 32);
    acc = __builtin_amdgcn_mfma_f32_16x16x32_bf16(av, bv, acc, 0, 0, 0);
  }
  const int col = nt * 16 + r16;
  const float bias = lb[col];
  #pragma unroll
  for (int rr = 0; rr < 4; ++rr) {
    const int m = mt * 16 + kg * 4 + rr;
    logits[(size_t)m * 48 + col] = acc[rr] + bias;
  }
}

// ---- CRF partition: one block (1 wave) per example ----
__global__ void k_crf_part(const float* __restrict__ logits, const float* __restrict__ trans,
                           const float* __restrict__ start, const float* __restrict__ endt,
                           float* __restrict__ logz) {
  const int b = blockIdx.x;
  const int j = threadIdx.x;  // 64 threads, j<48 active
  __shared__ float tr[NTAGS * NTAGS];
  __shared__ float alpha[NTAGS];
  for (int i = j; i < NTAGS * NTAGS; i += 64) tr[i] = trans[i];
  if (j < NTAGS) alpha[j] = start[j] + logits[(size_t)b * 48 + j];
  __syncthreads();
  for (int t = 1; t < TT; ++t) {
    float newv = 0.f;
    if (j < NTAGS) {
      float m = -1e30f;
      #pragma unroll 8
      for (int i = 0; i < NTAGS; ++i) m = fmaxf(m, alpha[i] + tr[i * NTAGS + j]);
      float s = 0.f;
      #pragma unroll 8
      for (int i = 0; i < NTAGS; ++i) s += __expf(alpha[i] + tr[i * NTAGS + j] - m);
      newv = m + __logf(s) + logits[((size_t)t * BB + b) * 48 + j];
    }
    __syncthreads();
    if (j < NTAGS) alpha[j] = newv;
    __syncthreads();
  }
  float v = (j < NTAGS) ? alpha[j] + endt[j] : -1e30f;
  float m = v;
  for (int o = 32; o; o >>= 1) m = fmaxf(m, __shfl_xor(m, o));
  float e = (j < NTAGS) ? __expf(v - m) : 0.f;
  for (int o = 32; o; o >>= 1) e += __shfl_xor(e, o);
  if (j == 0) logz[b] = m + __logf(e);
}

// ---- CRF gold-path score: one block (1 wave) per example ----
__global__ void k_crf_joint(const float* __restrict__ logits, const int* __restrict__ tags,
                            const float* __restrict__ trans, const float* __restrict__ start,
                            const float* __restrict__ endt, float* __restrict__ joint) {
  const int b = blockIdx.x;
  const int tid = threadIdx.x;
  float p = 0.f;
  for (int t = tid; t < TT - 1; t += 64) {
    const int tt = tags[b * TT + t], tn = tags[b * TT + t + 1];
    p += trans[tt * NTAGS + tn] + logits[((size_t)t * BB + b) * 48 + tt];
  }
  for (int o = 32; o; o >>= 1) p += __shfl_xor(p, o);
  if (tid == 0) {
    const int t0 = tags[b * TT];
    const int tl = tags[b * TT + TT - 1];
    p += start[t0] + endt[tl] + logits[((size_t)(TT - 1) * BB + b) * 48 + tl];
    joint[b] = p;
  }
}

__global__ void k_final(const float* __restrict__ joint, const float* __restrict__ logz,
                        float* __restrict__ out) {
  const int tid = threadIdx.x;
  float v = joint[tid] - logz[tid];
  for (int o = 32; o; o >>= 1) v += __shfl_xor(v, o);
  if (tid == 0) out[0] = -v;
}

// ---- workspace layout (bytes, all 256-aligned) ----
#define X_OFF    ((size_t)0)                         // T*B*512 bf16   = 33,554,432
#define W1_OFF   ((size_t)33554432)                  // 2*2048*1024*2  =  8,388,608
#define W2_OFF   ((size_t)41943040)                  // 2*1024*1280*2  =  5,242,880
#define WL_OFF   ((size_t)47185920)                  // 48*512*2       =     49,152
#define BS1_OFF  ((size_t)47235072)                  // 2*2048*4       =     16,384
#define BS2_OFF  ((size_t)47251456)                  // 2*1024*4       =      8,192
#define OUT1_OFF ((size_t)47259648)                  // T*B*1024*2     = 67,108,864
#define OUT2_OFF ((size_t)114368512)                 // T*B*512*2      = 33,554,432
#define LG_OFF   ((size_t)147922944)                 // T*B*48*4       =  6,291,456
#define H1B_OFF  ((size_t)154214400)                 // 2*2*64*512*2   =    262,144
#define C1B_OFF  ((size_t)154476544)                 // 2*64*512*4     =    262,144
#define H2B_OFF  ((size_t)154738688)                 // 2*2*64*256*2   =    131,072
#define C2B_OFF  ((size_t)154869760)                 // 2*64*256*4     =    131,072
#define LZ_OFF   ((size_t)155000832)                 // 64*4 (pad 256)
#define JT_OFF   ((size_t)155001088)
#define BAR_OFF  ((size_t)155001344)                 // 4*512*4 = 8192
#define WS_NEED  ((size_t)155009536)

extern "C" void kernel_launch(void* const* d_in, const int* in_sizes, int n_in,
                              void* d_out, int out_size, void* d_ws, size_t ws_size,
                              hipStream_t stream) {
  if (ws_size < WS_NEED) return;
  const int*   seq    = (const int*)d_in[0];
  const int*   tags   = (const int*)d_in[1];
  const float* h0     = (const float*)d_in[3];
  const float* c0     = (const float*)d_in[4];
  const float* h1     = (const float*)d_in[5];
  const float* c1     = (const float*)d_in[6];
  const float* emb    = (const float*)d_in[7];
  const float* lin_w  = (const float*)d_in[8];
  const float* lin_b  = (const float*)d_in[9];
  const float* trans  = (const float*)d_in[10];
  const float* start_t= (const float*)d_in[11];
  const float* end_t  = (const float*)d_in[12];
  const float* wih1f  = (const float*)d_in[13];
  const float* whh1f  = (const float*)d_in[14];
  const float* bih1f  = (const float*)d_in[15];
  const float* bhh1f  = (const float*)d_in[16];
  const float* wih1b  = (const float*)d_in[17];
  const float* whh1b  = (const float*)d_in[18];
  const float* bih1b  = (const float*)d_in[19];
  const float* bhh1b  = (const float*)d_in[20];
  const float* wih2f  = (const float*)d_in[21];
  const float* whh2f  = (const float*)d_in[22];
  const float* bih2f  = (const float*)d_in[23];
  const float* bhh2f  = (const float*)d_in[24];
  const float* wih2b  = (const float*)d_in[25];
  const float* whh2b  = (const float*)d_in[26];
  const float* bih2b  = (const float*)d_in[27];
  const float* bhh2b  = (const float*)d_in[28];

  char* ws = (char*)d_ws;
  unsigned short* x    = (unsigned short*)(ws + X_OFF);
  unsigned short* W1   = (unsigned short*)(ws + W1_OFF);
  unsigned short* W2   = (unsigned short*)(ws + W2_OFF);
  unsigned short* WL   = (unsigned short*)(ws + WL_OFF);
  float*          bs1  = (float*)(ws + BS1_OFF);
  float*          bs2  = (float*)(ws + BS2_OFF);
  unsigned short* out1 = (unsigned short*)(ws + OUT1_OFF);
  unsigned short* out2 = (unsigned short*)(ws + OUT2_OFF);
  float*          lg   = (float*)(ws + LG_OFF);
  unsigned short* h1b  = (unsigned short*)(ws + H1B_OFF);
  float*          c1b  = (float*)(ws + C1B_OFF);
  unsigned short* h2b  = (unsigned short*)(ws + H2B_OFF);
  float*          c2b  = (float*)(ws + C2B_OFF);
  float*          lz   = (float*)(ws + LZ_OFF);
  float*          jt   = (float*)(ws + JT_OFF);
  unsigned*       bars = (unsigned*)(ws + BAR_OFF);

  hipMemsetAsync(bars, 0, 4 * TT * sizeof(unsigned), stream);

  k_gather_x<<<16384, 256, 0, stream>>>(emb, seq, x);
  k_conv_w1<<<4096, 256, 0, stream>>>(wih1f, whh1f, wih1b, whh1b, W1);
  k_conv_w2<<<2560, 256, 0, stream>>>(wih2f, whh2f, wih2b, whh2b, W2);
  k_misc_init<<<888, 256, 0, stream>>>(lin_w, h0, c0, h1, c1,
                                       bih1f, bhh1f, bih1b, bhh1b,
                                       bih2f, bhh2f, bih2b, bhh2b,
                                       WL, bs1, bs2, h1b, c1b, h2b, c2b);
  k_lstm1<<<64, 256, 0, stream>>>(x, W1, bs1, h1b, c1b, out1, bars);
  k_lstm2<<<32, 256, 0, stream>>>(out1, W2, bs2, h2b, c2b, out2, bars);
  k_linear<<<1536, 256, 0, stream>>>(out2, WL, lin_b, lg);
  k_crf_part<<<64, 64, 0, stream>>>(lg, trans, start_t, end_t, lz);
  k_crf_joint<<<64, 64, 0, stream>>>(lg, tags, trans, start_t, end_t, jt);
  k_final<<<1, 64, 0, stream>>>(jt, lz, (float*)d_out);
}

// Round 2
// 24153.207 us; speedup vs baseline: 1.1058x; 1.1058x over previous
//
#include <hip/hip_runtime.h>
#include <stdint.h>

#define TT 512
#define BB 64
#define NTAGS 48

typedef __attribute__((ext_vector_type(8))) short bf16x8;
typedef __attribute__((ext_vector_type(4))) float f32x4;

__device__ inline unsigned short f2bf(float f) {
  union { float f; unsigned u; } v; v.f = f;
  unsigned r = v.u + 0x7fffu + ((v.u >> 16) & 1u);
  return (unsigned short)(r >> 16);
}
__device__ inline float sigf(float x) { return 1.0f / (1.0f + __expf(-x)); }
__device__ inline float tanhfast(float x) { return 1.0f - 2.0f / (__expf(2.0f * x) + 1.0f); }

// ---- x[t][b][k] = bf16(embed[seq[b][t]][k]) ----
__global__ void k_gather_x(const float* __restrict__ emb, const int* __restrict__ seq,
                           unsigned short* __restrict__ x) {
  size_t i4 = ((size_t)blockIdx.x * 256 + threadIdx.x) * 4;  // < T*B*512
  int r = (int)(i4 >> 9);
  int k = (int)(i4 & 511);
  int t = r >> 6, b = r & 63;
  int tok = seq[b * TT + t];
  float4 v = *(const float4*)(emb + (size_t)tok * 512 + k);
  unsigned short* dst = x + i4;
  dst[0] = f2bf(v.x); dst[1] = f2bf(v.y); dst[2] = f2bf(v.z); dst[3] = f2bf(v.w);
}

// ---- generic f32 -> bf16 convert, 4 elems/thread ----
__global__ void k_conv(const float* __restrict__ s, unsigned short* __restrict__ d, int n4) {
  int i = blockIdx.x * 256 + threadIdx.x;
  if (i >= n4) return;
  float4 v = *(const float4*)(s + (size_t)i * 4);
  unsigned short* dst = d + (size_t)i * 4;
  dst[0] = f2bf(v.x); dst[1] = f2bf(v.y); dst[2] = f2bf(v.z); dst[3] = f2bf(v.w);
}

// ---- bias sums + initial h states (bf16, parity-0 slot of hbuf) ----
__global__ void k_misc2(const float* __restrict__ h0, const float* __restrict__ h1,
                        const float* __restrict__ bi1f, const float* __restrict__ bh1f,
                        const float* __restrict__ bi1b, const float* __restrict__ bh1b,
                        const float* __restrict__ bi2f, const float* __restrict__ bh2f,
                        const float* __restrict__ bi2b, const float* __restrict__ bh2b,
                        float* __restrict__ bs1, float* __restrict__ bs2,
                        unsigned short* __restrict__ hb1, unsigned short* __restrict__ hb2) {
  int i = blockIdx.x * 256 + threadIdx.x;
  if (i < 4096) { int dd = i >> 11, n = i & 2047; bs1[i] = dd ? (bi1b[n] + bh1b[n]) : (bi1f[n] + bh1f[n]); return; }
  i -= 4096;
  if (i < 2048) { int dd = i >> 10, n = i & 1023; bs2[i] = dd ? (bi2b[n] + bh2b[n]) : (bi2f[n] + bh2f[n]); return; }
  i -= 2048;
  if (i < 65536) { hb1[i] = f2bf(h0[i]); return; }   // hbuf1 parity 0: [2][64][512]
  i -= 65536;
  if (i < 32768) { hb2[i] = f2bf(h1[i]); return; }   // hbuf2 parity 0: [2][64][256]
}

// ---- persistent BiLSTM layer: block = (dir, 16-unit group) x 64 batches ----
// 8 waves: wv 0..3 = h-waves (batch tile = wv), wv 4..7 = x-waves (gate = wv-4, 1 step ahead)
template<int KX, int H, int NBLKD>
__global__ __launch_bounds__(512) void k_lstm(
    const unsigned short* __restrict__ xin,   // [T][64][KX] bf16
    const unsigned short* __restrict__ Wih,   // [2][4H][KX] bf16
    const unsigned short* __restrict__ Whh,   // [2][4H][H]  bf16
    const float* __restrict__ bsum,           // [2][4H]
    const float* __restrict__ cinit,          // [2][64][H] f32 (input, read-only)
    unsigned short* __restrict__ hbuf,        // [2 parity][2 dir][64][H] bf16
    unsigned short* __restrict__ outp,        // [T][64][2H] bf16
    unsigned* __restrict__ bars) {            // [2 dir][TT]
  const int dir = blockIdx.x / NBLKD;
  const int ug  = blockIdx.x % NBLKD;
  const int wv = threadIdx.x >> 6, lane = threadIdx.x & 63;
  const int r16 = lane & 15, kg = lane >> 4;

  __shared__ unsigned short Wl[64 * H];       // W_hh slice, XOR-swizzled
  __shared__ float xacc[2][4][4][256];        // [buf][gate][bt][lane*4+rr]
  __shared__ unsigned done[2];
  if (threadIdx.x == 0) { done[0] = 0u; done[1] = 0u; }

  // stage W_hh rows (gate-major: lrow = g*16+u) with bank-conflict swizzle
  for (int c = threadIdx.x; c < 64 * (H / 8); c += 512) {
    const int lrow = c / (H / 8), k8 = c % (H / 8);
    bf16x8 v = *(const bf16x8*)(Whh + ((size_t)(dir * 4 * H + (lrow >> 4) * H + ug * 16 + (lrow & 15))) * H + k8 * 8);
    const int addr = ((lrow * H + k8 * 8) * 2) ^ ((lrow & 7) << 4);
    *(bf16x8*)((char*)Wl + addr) = v;
  }

  unsigned* const mybars = bars + dir * TT;
  float creg[4];

  auto xgemm = [&](int sn) {
    const int gg = wv - 4;
    const int rowg = dir * 4 * H + gg * H + ug * 16 + r16;
    const unsigned short* wrow = Wih + (size_t)rowg * KX + kg * 8;
    const float bias = bsum[rowg];
    const int t = dir ? (TT - 1 - sn) : sn;
    const unsigned short* xa = xin + (size_t)t * 64 * KX + kg * 8;
    f32x4 A0 = {bias, bias, bias, bias}, A1 = A0, A2 = A0, A3 = A0;
    for (int kk = 0; kk < KX / 32; ++kk) {
      bf16x8 w  = *(const bf16x8*)(wrow + kk * 32);
      bf16x8 a0 = *(const bf16x8*)(xa + (size_t)(0 * 16 + r16) * KX + kk * 32);
      bf16x8 a1 = *(const bf16x8*)(xa + (size_t)(1 * 16 + r16) * KX + kk * 32);
      bf16x8 a2 = *(const bf16x8*)(xa + (size_t)(2 * 16 + r16) * KX + kk * 32);
      bf16x8 a3 = *(const bf16x8*)(xa + (size_t)(3 * 16 + r16) * KX + kk * 32);
      A0 = __builtin_amdgcn_mfma_f32_16x16x32_bf16(a0, w, A0, 0, 0, 0);
      A1 = __builtin_amdgcn_mfma_f32_16x16x32_bf16(a1, w, A1, 0, 0, 0);
      A2 = __builtin_amdgcn_mfma_f32_16x16x32_bf16(a2, w, A2, 0, 0, 0);
      A3 = __builtin_amdgcn_mfma_f32_16x16x32_bf16(a3, w, A3, 0, 0, 0);
    }
    const int p = sn & 1;
    *(f32x4*)&xacc[p][gg][0][lane * 4] = A0;
    *(f32x4*)&xacc[p][gg][1][lane * 4] = A1;
    *(f32x4*)&xacc[p][gg][2][lane * 4] = A2;
    *(f32x4*)&xacc[p][gg][3][lane * 4] = A3;
  };

  if (wv < 4) {
    const int batch0 = wv * 16 + kg * 4;
    #pragma unroll
    for (int rr = 0; rr < 4; ++rr)
      creg[rr] = cinit[((size_t)dir * 64 + batch0 + rr) * H + ug * 16 + r16];
  } else {
    xgemm(0);
  }

  for (int s = 0; s < TT; ++s) {
    __syncthreads();  // xacc[s&1] ready; previous consumers done with xacc[(s+1)&1]
    if (wv >= 4) {
      if (s + 1 < TT) xgemm(s + 1);
    } else {
      if (s > 0 && lane == 0) {
        while (__hip_atomic_load(&mybars[s - 1], __ATOMIC_ACQUIRE, __HIP_MEMORY_SCOPE_AGENT) < (unsigned)NBLKD)
          __builtin_amdgcn_s_sleep(1);
      }
      const int p = s & 1;
      const int bt = wv;
      f32x4 A0 = *(const f32x4*)&xacc[p][0][bt][lane * 4];
      f32x4 A1 = *(const f32x4*)&xacc[p][1][bt][lane * 4];
      f32x4 A2 = *(const f32x4*)&xacc[p][2][bt][lane * 4];
      f32x4 A3 = *(const f32x4*)&xacc[p][3][bt][lane * 4];
      const unsigned short* hrow = hbuf + (((size_t)p * 2 + dir) * 64 + bt * 16 + r16) * H + kg * 8;
      const int sw = (r16 & 7) << 4;
      #pragma unroll
      for (int kk = 0; kk < H / 32; ++kk) {
        bf16x8 av = *(const bf16x8*)(hrow + kk * 32);
        bf16x8 b0 = *(const bf16x8*)((const char*)Wl + ((((0 * 16 + r16) * H + kk * 32 + kg * 8) * 2) ^ sw));
        bf16x8 b1 = *(const bf16x8*)((const char*)Wl + ((((1 * 16 + r16) * H + kk * 32 + kg * 8) * 2) ^ sw));
        bf16x8 b2 = *(const bf16x8*)((const char*)Wl + ((((2 * 16 + r16) * H + kk * 32 + kg * 8) * 2) ^ sw));
        bf16x8 b3 = *(const bf16x8*)((const char*)Wl + ((((3 * 16 + r16) * H + kk * 32 + kg * 8) * 2) ^ sw));
        A0 = __builtin_amdgcn_mfma_f32_16x16x32_bf16(av, b0, A0, 0, 0, 0);
        A1 = __builtin_amdgcn_mfma_f32_16x16x32_bf16(av, b1, A1, 0, 0, 0);
        A2 = __builtin_amdgcn_mfma_f32_16x16x32_bf16(av, b2, A2, 0, 0, 0);
        A3 = __builtin_amdgcn_mfma_f32_16x16x32_bf16(av, b3, A3, 0, 0, 0);
      }
      const int t = dir ? (TT - 1 - s) : s;
      const int batch0 = bt * 16 + kg * 4;
      unsigned short* hw = hbuf + ((size_t)(p ^ 1) * 2 + dir) * 64 * H;
      #pragma unroll
      for (int rr = 0; rr < 4; ++rr) {
        float cn = sigf(A1[rr]) * creg[rr] + sigf(A0[rr]) * tanhfast(A2[rr]);
        float hn = sigf(A3[rr]) * tanhfast(cn);
        creg[rr] = cn;
        unsigned short hb = f2bf(hn);
        hw[(size_t)(batch0 + rr) * H + ug * 16 + r16] = hb;
        outp[((size_t)t * 64 + batch0 + rr) * (2 * H) + dir * H + ug * 16 + r16] = hb;
      }
      __threadfence();
      if (lane == 0) {
        unsigned old = __hip_atomic_fetch_add(&done[p], 1u, __ATOMIC_ACQ_REL, __HIP_MEMORY_SCOPE_WORKGROUP);
        if (old == 3u) {
          done[p] = 0u;
          __hip_atomic_fetch_add(&mybars[s], 1u, __ATOMIC_RELEASE, __HIP_MEMORY_SCOPE_AGENT);
        }
      }
    }
  }
}

// ---- logits = out2 @ lin_w^T + lin_b : [32768][48] f32 ----
__global__ __launch_bounds__(256) void k_linear(const unsigned short* __restrict__ out2,
                                                const unsigned short* __restrict__ wl,
                                                const float* __restrict__ lb,
                                                float* __restrict__ logits) {
  const int wid = blockIdx.x * 4 + (threadIdx.x >> 6);  // < 6144
  const int lane = threadIdx.x & 63;
  const int mt = wid / 3, nt = wid % 3;
  const int r16 = lane & 15, kg = lane >> 4;
  const unsigned short* ar = out2 + ((size_t)mt * 16 + r16) * 512 + kg * 8;
  const unsigned short* br = wl + ((size_t)(nt * 16 + r16)) * 512 + kg * 8;
  f32x4 acc = {0.f, 0.f, 0.f, 0.f};
  #pragma unroll
  for (int kk = 0; kk < 16; ++kk) {
    bf16x8 av = *(const bf16x8*)(ar + kk * 32);
    bf16x8 bv = *(const bf16x8*)(br + kk * 32);
    acc = __builtin_amdgcn_mfma_f32_16x16x32_bf16(av, bv, acc, 0, 0, 0);
  }
  const int col = nt * 16 + r16;
  const float bias = lb[col];
  #pragma unroll
  for (int rr = 0; rr < 4; ++rr) {
    const int m = mt * 16 + kg * 4 + rr;
    logits[(size_t)m * 48 + col] = acc[rr] + bias;
  }
}

// ---- CRF partition: one block (1 wave) per example ----
__global__ void k_crf_part(const float* __restrict__ logits, const float* __restrict__ trans,
                           const float* __restrict__ start, const float* __restrict__ endt,
                           float* __restrict__ logz) {
  const int b = blockIdx.x;
  const int j = threadIdx.x;  // 64 threads, j<48 active
  __shared__ float tr[NTAGS * NTAGS];
  __shared__ float alpha[NTAGS];
  for (int i = j; i < NTAGS * NTAGS; i += 64) tr[i] = trans[i];
  if (j < NTAGS) alpha[j] = start[j] + logits[(size_t)b * 48 + j];
  __syncthreads();
  for (int t = 1; t < TT; ++t) {
    float newv = 0.f;
    if (j < NTAGS) {
      float m = -1e30f;
      #pragma unroll 8
      for (int i = 0; i < NTAGS; ++i) m = fmaxf(m, alpha[i] + tr[i * NTAGS + j]);
      float s = 0.f;
      #pragma unroll 8
      for (int i = 0; i < NTAGS; ++i) s += __expf(alpha[i] + tr[i * NTAGS + j] - m);
      newv = m + __logf(s) + logits[((size_t)t * BB + b) * 48 + j];
    }
    __syncthreads();
    if (j < NTAGS) alpha[j] = newv;
    __syncthreads();
  }
  float v = (j < NTAGS) ? alpha[j] + endt[j] : -1e30f;
  float m = v;
  for (int o = 32; o; o >>= 1) m = fmaxf(m, __shfl_xor(m, o));
  float e = (j < NTAGS) ? __expf(v - m) : 0.f;
  for (int o = 32; o; o >>= 1) e += __shfl_xor(e, o);
  if (j == 0) logz[b] = m + __logf(e);
}

// ---- CRF gold-path score: one block (1 wave) per example ----
__global__ void k_crf_joint(const float* __restrict__ logits, const int* __restrict__ tags,
                            const float* __restrict__ trans, const float* __restrict__ start,
                            const float* __restrict__ endt, float* __restrict__ joint) {
  const int b = blockIdx.x;
  const int tid = threadIdx.x;
  float p = 0.f;
  for (int t = tid; t < TT - 1; t += 64) {
    const int tt = tags[b * TT + t], tn = tags[b * TT + t + 1];
    p += trans[tt * NTAGS + tn] + logits[((size_t)t * BB + b) * 48 + tt];
  }
  for (int o = 32; o; o >>= 1) p += __shfl_xor(p, o);
  if (tid == 0) {
    const int t0 = tags[b * TT];
    const int tl = tags[b * TT + TT - 1];
    p += start[t0] + endt[tl] + logits[((size_t)(TT - 1) * BB + b) * 48 + tl];
    joint[b] = p;
  }
}

__global__ void k_final(const float* __restrict__ joint, const float* __restrict__ logz,
                        float* __restrict__ out) {
  const int tid = threadIdx.x;
  float v = joint[tid] - logz[tid];
  for (int o = 32; o; o >>= 1) v += __shfl_xor(v, o);
  if (tid == 0) out[0] = -v;
}

// ---- workspace layout (bytes) ----
#define X_OFF    ((size_t)0)              // 33,554,432   x bf16 [T][64][512]
#define WIH1_OFF ((size_t)33554432)       //  4,194,304   [2][2048][512]
#define WHH1_OFF ((size_t)37748736)       //  4,194,304   [2][2048][512]
#define WIH2_OFF ((size_t)41943040)       //  4,194,304   [2][1024][1024]
#define WHH2_OFF ((size_t)46137344)       //  1,048,576   [2][1024][256]
#define WL_OFF   ((size_t)47185920)       //     49,152
#define BS1_OFF  ((size_t)47235072)       //     16,384
#define BS2_OFF  ((size_t)47251456)       //      8,192
#define OUT1_OFF ((size_t)47259648)       // 67,108,864   [T][64][1024] bf16
#define OUT2_OFF ((size_t)114368512)      // 33,554,432   [T][64][512] bf16
#define LG_OFF   ((size_t)147922944)      //  6,291,456   [32768][48] f32
#define HB1_OFF  ((size_t)154214400)      //    262,144   [2][2][64][512] bf16
#define HB2_OFF  ((size_t)154476544)      //    131,072   [2][2][64][256] bf16
#define LZ_OFF   ((size_t)154607616)      //        256
#define JT_OFF   ((size_t)154607872)      //        256
#define BAR_OFF  ((size_t)154608128)      //     16,384
#define WS_NEED  ((size_t)154624512)

extern "C" void kernel_launch(void* const* d_in, const int* in_sizes, int n_in,
                              void* d_out, int out_size, void* d_ws, size_t ws_size,
                              hipStream_t stream) {
  if (ws_size < WS_NEED) return;
  const int*   seq    = (const int*)d_in[0];
  const int*   tags   = (const int*)d_in[1];
  const float* h0     = (const float*)d_in[3];
  const float* c0     = (const float*)d_in[4];
  const float* h1     = (const float*)d_in[5];
  const float* c1     = (const float*)d_in[6];
  const float* emb    = (const float*)d_in[7];
  const float* lin_w  = (const float*)d_in[8];
  const float* lin_b  = (const float*)d_in[9];
  const float* trans  = (const float*)d_in[10];
  const float* start_t= (const float*)d_in[11];
  const float* end_t  = (const float*)d_in[12];
  const float* wih1f  = (const float*)d_in[13];
  const float* whh1f  = (const float*)d_in[14];
  const float* bih1f  = (const float*)d_in[15];
  const float* bhh1f  = (const float*)d_in[16];
  const float* wih1b  = (const float*)d_in[17];
  const float* whh1b  = (const float*)d_in[18];
  const float* bih1b  = (const float*)d_in[19];
  const float* bhh1b  = (const float*)d_in[20];
  const float* wih2f  = (const float*)d_in[21];
  const float* whh2f  = (const float*)d_in[22];
  const float* bih2f  = (const float*)d_in[23];
  const float* bhh2f  = (const float*)d_in[24];
  const float* wih2b  = (const float*)d_in[25];
  const float* whh2b  = (const float*)d_in[26];
  const float* bih2b  = (const float*)d_in[27];
  const float* bhh2b  = (const float*)d_in[28];

  char* ws = (char*)d_ws;
  unsigned short* x    = (unsigned short*)(ws + X_OFF);
  unsigned short* Wih1 = (unsigned short*)(ws + WIH1_OFF);
  unsigned short* Whh1 = (unsigned short*)(ws + WHH1_OFF);
  unsigned short* Wih2 = (unsigned short*)(ws + WIH2_OFF);
  unsigned short* Whh2 = (unsigned short*)(ws + WHH2_OFF);
  unsigned short* WL   = (unsigned short*)(ws + WL_OFF);
  float*          bs1  = (float*)(ws + BS1_OFF);
  float*          bs2  = (float*)(ws + BS2_OFF);
  unsigned short* out1 = (unsigned short*)(ws + OUT1_OFF);
  unsigned short* out2 = (unsigned short*)(ws + OUT2_OFF);
  float*          lg   = (float*)(ws + LG_OFF);
  unsigned short* hb1  = (unsigned short*)(ws + HB1_OFF);
  unsigned short* hb2  = (unsigned short*)(ws + HB2_OFF);
  float*          lz   = (float*)(ws + LZ_OFF);
  float*          jt   = (float*)(ws + JT_OFF);
  unsigned*       bars = (unsigned*)(ws + BAR_OFF);

  hipMemsetAsync(bars, 0, 16384, stream);

  k_gather_x<<<16384, 256, 0, stream>>>(emb, seq, x);
  // weight conversions (f32 -> bf16, row-major)
  k_conv<<<1024, 256, 0, stream>>>(wih1f, Wih1,                 262144);
  k_conv<<<1024, 256, 0, stream>>>(wih1b, Wih1 + 2048 * 512,    262144);
  k_conv<<<1024, 256, 0, stream>>>(whh1f, Whh1,                 262144);
  k_conv<<<1024, 256, 0, stream>>>(whh1b, Whh1 + 2048 * 512,    262144);
  k_conv<<<1024, 256, 0, stream>>>(wih2f, Wih2,                 262144);
  k_conv<<<1024, 256, 0, stream>>>(wih2b, Wih2 + 1024 * 1024,   262144);
  k_conv<<<256, 256, 0, stream>>>(whh2f, Whh2,                  65536);
  k_conv<<<256, 256, 0, stream>>>(whh2b, Whh2 + 1024 * 256,     65536);
  k_conv<<<24, 256, 0, stream>>>(lin_w, WL,                     6144);
  k_misc2<<<408, 256, 0, stream>>>(h0, h1, bih1f, bhh1f, bih1b, bhh1b,
                                   bih2f, bhh2f, bih2b, bhh2b, bs1, bs2, hb1, hb2);

  k_lstm<512, 512, 32><<<64, 512, 0, stream>>>(x, Wih1, Whh1, bs1, c0, hb1, out1, bars);
  k_lstm<1024, 256, 16><<<32, 512, 0, stream>>>(out1, Wih2, Whh2, bs2, c1, hb2, out2, bars + 1024);

  k_linear<<<1536, 256, 0, stream>>>(out2, WL, lin_b, lg);
  k_crf_part<<<64, 64, 0, stream>>>(lg, trans, start_t, end_t, lz);
  k_crf_joint<<<64, 64, 0, stream>>>(lg, tags, trans, start_t, end_t, jt);
  k_final<<<1, 64, 0, stream>>>(jt, lz, (float*)d_out);
}